// Round 1
// baseline (1465.287 us; speedup 1.0000x reference)
//
#include <hip/hip_runtime.h>

// ResidualAttentionBlock on MI355X (gfx950).
// D=768 H=12 HD=64 NQ=100 KV=257 SEQ=357 BS=32.
// Round 1: correctness-first. bf16 MFMA GEMMs (16x16x32), vector online-softmax attention.

typedef short bf16x8 __attribute__((ext_vector_type(8)));
typedef float f32x4 __attribute__((ext_vector_type(4)));
typedef unsigned short u16;

__device__ __forceinline__ u16 f2b(float f) {
    unsigned u = __builtin_bit_cast(unsigned, f);
    u = (u + 0x7fffu + ((u >> 16) & 1u)) >> 16;  // RNE
    return (u16)u;
}
__device__ __forceinline__ float b2f(u16 h) {
    unsigned u = ((unsigned)h) << 16;
    return __builtin_bit_cast(float, u);
}

// ---------------- f32 -> bf16 conversion (weights) ----------------
__global__ void cvt_kernel(const float* __restrict__ in, u16* __restrict__ out, int n4) {
    int i = blockIdx.x * 256 + threadIdx.x;
    int stride = gridDim.x * 256;
    for (; i < n4; i += stride) {
        float4 v = ((const float4*)in)[i];
        ushort4 o;
        o.x = f2b(v.x); o.y = f2b(v.y); o.z = f2b(v.z); o.w = f2b(v.w);
        ((ushort4*)out)[i] = o;
    }
}

// ---------------- LayerNorm (fp32 in, bf16 out), one wave per row of 768 ----------------
__global__ __launch_bounds__(256) void ln_kernel(
    const float* __restrict__ in, const float* __restrict__ g, const float* __restrict__ be,
    u16* __restrict__ out, int nrows)
{
    int row = blockIdx.x * 4 + (threadIdx.x >> 6);
    int lane = threadIdx.x & 63;
    if (row >= nrows) return;
    const float* p = in + (size_t)row * 768;
    float4 a0 = *(const float4*)(p + lane * 4);
    float4 a1 = *(const float4*)(p + 256 + lane * 4);
    float4 a2 = *(const float4*)(p + 512 + lane * 4);
    float s = a0.x + a0.y + a0.z + a0.w + a1.x + a1.y + a1.z + a1.w + a2.x + a2.y + a2.z + a2.w;
    for (int o = 32; o; o >>= 1) s += __shfl_xor(s, o);
    float mean = s * (1.f / 768.f);
    float vs = 0.f;
#define SQA(t) { float dx; dx = t.x-mean; vs += dx*dx; dx = t.y-mean; vs += dx*dx; dx = t.z-mean; vs += dx*dx; dx = t.w-mean; vs += dx*dx; }
    SQA(a0) SQA(a1) SQA(a2)
#undef SQA
    for (int o = 32; o; o >>= 1) vs += __shfl_xor(vs, o);
    float rstd = rsqrtf(vs * (1.f / 768.f) + 1e-5f);
    u16* orow = out + (size_t)row * 768;
#pragma unroll
    for (int i = 0; i < 3; ++i) {
        int d = i * 256 + lane * 4;
        float4 av = (i == 0) ? a0 : ((i == 1) ? a1 : a2);
        float4 gv = *(const float4*)(g + d);
        float4 bv = *(const float4*)(be + d);
        ushort4 ov;
        ov.x = f2b((av.x - mean) * rstd * gv.x + bv.x);
        ov.y = f2b((av.y - mean) * rstd * gv.y + bv.y);
        ov.z = f2b((av.z - mean) * rstd * gv.z + bv.z);
        ov.w = f2b((av.w - mean) * rstd * gv.w + bv.w);
        *(ushort4*)(orow + d) = ov;
    }
}

// ---------------- bf16 MFMA GEMM: C[M][N] = A[M][K] @ B[N][K]^T + bias (+res) ----------------
// 128x128 tile, 4 waves (2x2), each wave 4x4 16x16 fragments. BK=32.
template<int ACT, int OUTBF, int RES>
__global__ __launch_bounds__(256) void gemm_bt(
    const u16* __restrict__ A, const u16* __restrict__ B,
    const float* __restrict__ bias, const float* __restrict__ res,
    void* __restrict__ Cp, int M, int N, int K)
{
    __shared__ u16 Al[128][40];  // pad 32->40 (80B row stride): 2-way banks on frag reads
    __shared__ u16 Bl[128][40];
    const int t = threadIdx.x;
    const int lane = t & 63, w = t >> 6;
    const int wr = w >> 1, wc = w & 1;
    const int m0 = blockIdx.x * 128, n0 = blockIdx.y * 128;
    const int fr = lane & 15, fg = lane >> 4;
    f32x4 acc[4][4] = {};
    for (int k0 = 0; k0 < K; k0 += 32) {
#pragma unroll
        for (int it = 0; it < 2; ++it) {
            int c = t + it * 256;
            int r = c >> 2, cc = (c & 3) << 3;
            int ga = m0 + r; ga = ga < M ? ga : M - 1;
            *(uint4*)&Al[r][cc] = *(const uint4*)(A + (size_t)ga * K + k0 + cc);
            int gb = n0 + r; gb = gb < N ? gb : N - 1;
            *(uint4*)&Bl[r][cc] = *(const uint4*)(B + (size_t)gb * K + k0 + cc);
        }
        __syncthreads();
        bf16x8 af[4], bfr[4];
#pragma unroll
        for (int m = 0; m < 4; ++m) af[m] = *(const bf16x8*)&Al[wr * 64 + m * 16 + fr][fg * 8];
#pragma unroll
        for (int n = 0; n < 4; ++n) bfr[n] = *(const bf16x8*)&Bl[wc * 64 + n * 16 + fr][fg * 8];
#pragma unroll
        for (int m = 0; m < 4; ++m)
#pragma unroll
            for (int n = 0; n < 4; ++n)
                acc[m][n] = __builtin_amdgcn_mfma_f32_16x16x32_bf16(af[m], bfr[n], acc[m][n], 0, 0, 0);
        __syncthreads();
    }
    // Epilogue. C/D layout: col = lane&15, row = (lane>>4)*4 + r  [measured m89/m91]
#pragma unroll
    for (int m = 0; m < 4; ++m) {
#pragma unroll
        for (int n = 0; n < 4; ++n) {
            int col = n0 + wc * 64 + n * 16 + fr;
            float bv = bias[col];
#pragma unroll
            for (int r = 0; r < 4; ++r) {
                int row = m0 + wr * 64 + m * 16 + fg * 4 + r;
                if (row < M) {
                    float v = acc[m][n][r] + bv;
                    if (RES) v += res[(size_t)row * N + col];
                    if (ACT) v = v / (1.f + __expf(-1.702f * v));  // QuickGELU
                    if (OUTBF) ((u16*)Cp)[(size_t)row * N + col] = f2b(v);
                    else       ((float*)Cp)[(size_t)row * N + col] = v;
                }
            }
        }
    }
}

// ---------------- attention: one block per (b,h,half-of-queries) ----------------
// K/V for (b,h) staged in exactly 64KB LDS (keys 0..255) + key 256 in registers.
// Per wave: one query at a time; lane = key (QK phase) / lane = dim (PV phase).
__global__ __launch_bounds__(512) void attn_kernel(
    const u16* __restrict__ qkv,   // [257*32][2304] rows m*32+b; q|k|v at +0/+768/+1536
    const u16* __restrict__ nq,    // [100*32][768]  rows q*32+b
    const int* __restrict__ mask,  // [32][100][257], nonzero = blocked
    u16* __restrict__ out)         // [357*32][768]  rows q*32+b
{
    __shared__ u16 KT[64 * 256];   // KT[d*256+m] = K[m][d]
    __shared__ u16 Vl[256 * 64];   // Vl[m*64+d]
    const int bidx = blockIdx.x;
    const int split = bidx & 1, bh = bidx >> 1;
    const int b = bh / 12, h = bh % 12;
    const int t = threadIdx.x, lane = t & 63, wv = t >> 6;
    const u16* kbase = qkv + 768 + h * 64;
    const u16* vbase = qkv + 1536 + h * 64;
    for (int idx = t; idx < 256 * 64; idx += 512) {
        int m = idx >> 6, d = idx & 63;
        size_t go = (size_t)(m * 32 + b) * 2304;
        KT[d * 256 + m] = kbase[go + d];
        Vl[idx] = vbase[go + d];
    }
    float k256 = b2f(kbase[(size_t)(256 * 32 + b) * 2304 + lane]);
    float v256 = b2f(vbase[(size_t)(256 * 32 + b) * 2304 + lane]);
    __syncthreads();
    const int q0 = split * 179;
    const int q1 = split ? 357 : 179;
    for (int q = q0 + wv; q < q1; q += 8) {
        const bool is_mask = q < 100;
        const u16* qrow = is_mask ? (nq + (size_t)(q * 32 + b) * 768 + h * 64)
                                  : (qkv + (size_t)((q - 100) * 32 + b) * 2304 + h * 64);
        const int* mrow = mask + ((size_t)b * 100 + (is_mask ? q : 0)) * 257;
        float qd = b2f(qrow[lane]) * 0.125f;  // 1/sqrt(64)
        float mmax = -INFINITY, lsum = 0.f, accd = 0.f;
#pragma unroll 1
        for (int ch = 0; ch < 4; ++ch) {
            int key = ch * 64 + lane;
            float s = 0.f;
#pragma unroll
            for (int d = 0; d < 64; ++d)
                s = fmaf(__shfl(qd, d), b2f(KT[d * 256 + key]), s);
            if (is_mask && mrow[key] != 0) s = -INFINITY;
            float smax = s;
            for (int o = 32; o; o >>= 1) smax = fmaxf(smax, __shfl_xor(smax, o));
            float mnew = fmaxf(mmax, smax);
            float corr = (mnew == -INFINITY) ? 1.f : __expf(mmax - mnew);
            float pp = (s == -INFINITY) ? 0.f : __expf(s - mnew);
            float ps = pp;
            for (int o = 32; o; o >>= 1) ps += __shfl_xor(ps, o);
            lsum = lsum * corr + ps;
            accd *= corr;
#pragma unroll
            for (int m2 = 0; m2 < 64; ++m2)
                accd = fmaf(__shfl(pp, m2), b2f(Vl[(ch * 64 + m2) * 64 + lane]), accd);
            mmax = mnew;
        }
        {   // key 256 (registers)
            float s = qd * k256;
            for (int o = 32; o; o >>= 1) s += __shfl_xor(s, o);
            if (is_mask && mrow[256] != 0) s = -INFINITY;
            float mnew = fmaxf(mmax, s);
            float corr = (mnew == -INFINITY) ? 1.f : __expf(mmax - mnew);
            float pp = (s == -INFINITY) ? 0.f : __expf(s - mnew);
            lsum = lsum * corr + pp;
            accd = accd * corr + pp * v256;
            mmax = mnew;
        }
        out[(size_t)(q * 32 + b) * 768 + h * 64 + lane] = f2b(accd / lsum);
    }
}

// ---------------- launch ----------------
extern "C" void kernel_launch(void* const* d_in, const int* in_sizes, int n_in,
                              void* d_out, int out_size, void* d_ws, size_t ws_size,
                              hipStream_t stream)
{
    const float* y   = (const float*)d_in[0];
    const int*   msk = (const int*)  d_in[1];
    const float* ipw = (const float*)d_in[2];
    const float* ipb = (const float*)d_in[3];
    const float* nqw = (const float*)d_in[4];
    const float* nqb = (const float*)d_in[5];
    const float* ow  = (const float*)d_in[6];
    const float* ob  = (const float*)d_in[7];
    const float* l1g = (const float*)d_in[8];
    const float* l1b = (const float*)d_in[9];
    const float* l2g = (const float*)d_in[10];
    const float* l2b = (const float*)d_in[11];
    const float* fcw = (const float*)d_in[12];
    const float* fcb = (const float*)d_in[13];
    const float* pjw = (const float*)d_in[14];
    const float* pjb = (const float*)d_in[15];

    char* ws = (char*)d_ws;
    // phase-1 region [0, 77.9MB): x | qkv | new_q | attn_out  (dead after out-proj)
    u16* x_b   = (u16*)(ws + 0);          // 11424 x 768
    u16* qkv_b = (u16*)(ws + 17547264);   //  8224 x 2304
    u16* nq_b  = (u16*)(ws + 55443456);   //  3200 x 768
    u16* ao_b  = (u16*)(ws + 60358656);   // 11424 x 768
    u16* h1_b  = (u16*)(ws + 0);          // 11424 x 3072 (phase 2, overlaps phase-1 region)
    u16* h_b   = (u16*)(ws + 77905920);   // 11424 x 768
    u16* w_ip  = (u16*)(ws + 95453184);
    u16* w_nq  = (u16*)(ws + 98992128);
    u16* w_out = (u16*)(ws + 100171776);
    u16* w_fc  = (u16*)(ws + 101351424);
    u16* w_pj  = (u16*)(ws + 106070016);  // end 110,788,608 bytes
    float* out = (float*)d_out;

    cvt_kernel<<<1728, 256, 0, stream>>>(ipw, w_ip, 2304 * 768 / 4);
    cvt_kernel<<<576,  256, 0, stream>>>(nqw, w_nq, 768 * 768 / 4);
    cvt_kernel<<<576,  256, 0, stream>>>(ow,  w_out, 768 * 768 / 4);
    cvt_kernel<<<2304, 256, 0, stream>>>(fcw, w_fc, 3072 * 768 / 4);
    cvt_kernel<<<2304, 256, 0, stream>>>(pjw, w_pj, 3072 * 768 / 4);

    // x = LN1(y) -> bf16
    ln_kernel<<<2856, 256, 0, stream>>>(y, l1g, l1b, x_b, 11424);
    // qkv = x[100:] @ in_proj_w.T + b   (rows 3200..11423)
    gemm_bt<0, 1, 0><<<dim3(65, 18), 256, 0, stream>>>(x_b + (size_t)3200 * 768, w_ip, ipb, nullptr, qkv_b, 8224, 2304, 768);
    // new_q = x[:100] @ new_q_w.T + b
    gemm_bt<0, 1, 0><<<dim3(25, 6), 256, 0, stream>>>(x_b, w_nq, nqb, nullptr, nq_b, 3200, 768, 768);
    // attention (both masked-new_q rows 0..99 and clip rows 100..356)
    attn_kernel<<<768, 512, 0, stream>>>(qkv_b, nq_b, msk, ao_b);
    // y2 = y + attn_out @ out_w.T + out_b   -> d_out (f32)
    gemm_bt<0, 0, 1><<<dim3(90, 6), 256, 0, stream>>>(ao_b, w_out, ob, y, out, 11424, 768, 768);
    // h = LN2(y2) -> bf16
    ln_kernel<<<2856, 256, 0, stream>>>(out, l2g, l2b, h_b, 11424);
    // h1 = quickgelu(h @ fc_w.T + fc_b) -> bf16
    gemm_bt<1, 1, 0><<<dim3(90, 24), 256, 0, stream>>>(h_b, w_fc, fcb, nullptr, h1_b, 11424, 3072, 768);
    // out = y2 + h1 @ proj_w.T + proj_b
    gemm_bt<0, 0, 1><<<dim3(90, 6), 256, 0, stream>>>(h1_b, w_pj, pjb, out, out, 11424, 768, 3072);
}

// Round 2
// 526.148 us; speedup vs baseline: 2.7849x; 2.7849x over previous
//
#include <hip/hip_runtime.h>

// ResidualAttentionBlock on MI355X (gfx950).
// D=768 H=12 HD=64 NQ=100 KV=257 SEQ=357 BS=32.
// Round 2: MFMA attention (S^T = K*Q^T, O^T = V^T*P^T), bitmask-packed attention mask.

typedef short bf16x8 __attribute__((ext_vector_type(8)));
typedef float f32x4 __attribute__((ext_vector_type(4)));
typedef unsigned short u16;
typedef unsigned long long u64;

__device__ __forceinline__ u16 f2b(float f) {
    unsigned u = __builtin_bit_cast(unsigned, f);
    u = (u + 0x7fffu + ((u >> 16) & 1u)) >> 16;  // RNE
    return (u16)u;
}
__device__ __forceinline__ float b2f(u16 h) {
    unsigned u = ((unsigned)h) << 16;
    return __builtin_bit_cast(float, u);
}
__device__ __forceinline__ unsigned pack2(float a, float b) {
    return (unsigned)f2b(a) | ((unsigned)f2b(b) << 16);
}

// ---------------- f32 -> bf16 conversion (weights) ----------------
__global__ void cvt_kernel(const float* __restrict__ in, u16* __restrict__ out, int n4) {
    int i = blockIdx.x * 256 + threadIdx.x;
    int stride = gridDim.x * 256;
    for (; i < n4; i += stride) {
        float4 v = ((const float4*)in)[i];
        ushort4 o;
        o.x = f2b(v.x); o.y = f2b(v.y); o.z = f2b(v.z); o.w = f2b(v.w);
        ((ushort4*)out)[i] = o;
    }
}

// ---------------- mask -> packed bitmask [32*100][5] u64 ----------------
__global__ __launch_bounds__(256) void mask_pack(const int* __restrict__ m, u64* __restrict__ o) {
    int row = blockIdx.x * 4 + (threadIdx.x >> 6);
    int lane = threadIdx.x & 63;
    if (row >= 3200) return;
    const int* r = m + (size_t)row * 257;
    u64 w0 = __ballot(r[lane] != 0);
    u64 w1 = __ballot(r[64 + lane] != 0);
    u64 w2 = __ballot(r[128 + lane] != 0);
    u64 w3 = __ballot(r[192 + lane] != 0);
    u64 w4 = __ballot(lane == 0 && r[256] != 0);
    if (lane == 0) {
        u64* p = o + (size_t)row * 5;
        p[0] = w0; p[1] = w1; p[2] = w2; p[3] = w3; p[4] = w4;
    }
}

// ---------------- LayerNorm (fp32 in, bf16 out), one wave per row of 768 ----------------
__global__ __launch_bounds__(256) void ln_kernel(
    const float* __restrict__ in, const float* __restrict__ g, const float* __restrict__ be,
    u16* __restrict__ out, int nrows)
{
    int row = blockIdx.x * 4 + (threadIdx.x >> 6);
    int lane = threadIdx.x & 63;
    if (row >= nrows) return;
    const float* p = in + (size_t)row * 768;
    float4 a0 = *(const float4*)(p + lane * 4);
    float4 a1 = *(const float4*)(p + 256 + lane * 4);
    float4 a2 = *(const float4*)(p + 512 + lane * 4);
    float s = a0.x + a0.y + a0.z + a0.w + a1.x + a1.y + a1.z + a1.w + a2.x + a2.y + a2.z + a2.w;
    for (int o = 32; o; o >>= 1) s += __shfl_xor(s, o);
    float mean = s * (1.f / 768.f);
    float vs = 0.f;
#define SQA(t) { float dx; dx = t.x-mean; vs += dx*dx; dx = t.y-mean; vs += dx*dx; dx = t.z-mean; vs += dx*dx; dx = t.w-mean; vs += dx*dx; }
    SQA(a0) SQA(a1) SQA(a2)
#undef SQA
    for (int o = 32; o; o >>= 1) vs += __shfl_xor(vs, o);
    float rstd = rsqrtf(vs * (1.f / 768.f) + 1e-5f);
    u16* orow = out + (size_t)row * 768;
#pragma unroll
    for (int i = 0; i < 3; ++i) {
        int d = i * 256 + lane * 4;
        float4 av = (i == 0) ? a0 : ((i == 1) ? a1 : a2);
        float4 gv = *(const float4*)(g + d);
        float4 bv = *(const float4*)(be + d);
        ushort4 ov;
        ov.x = f2b((av.x - mean) * rstd * gv.x + bv.x);
        ov.y = f2b((av.y - mean) * rstd * gv.y + bv.y);
        ov.z = f2b((av.z - mean) * rstd * gv.z + bv.z);
        ov.w = f2b((av.w - mean) * rstd * gv.w + bv.w);
        *(ushort4*)(orow + d) = ov;
    }
}

// ---------------- bf16 MFMA GEMM: C[M][N] = A[M][K] @ B[N][K]^T + bias (+res) ----------------
template<int ACT, int OUTBF, int RES>
__global__ __launch_bounds__(256) void gemm_bt(
    const u16* __restrict__ A, const u16* __restrict__ B,
    const float* __restrict__ bias, const float* __restrict__ res,
    void* __restrict__ Cp, int M, int N, int K)
{
    __shared__ u16 Al[128][40];
    __shared__ u16 Bl[128][40];
    const int t = threadIdx.x;
    const int lane = t & 63, w = t >> 6;
    const int wr = w >> 1, wc = w & 1;
    const int m0 = blockIdx.x * 128, n0 = blockIdx.y * 128;
    const int fr = lane & 15, fg = lane >> 4;
    f32x4 acc[4][4] = {};
    for (int k0 = 0; k0 < K; k0 += 32) {
#pragma unroll
        for (int it = 0; it < 2; ++it) {
            int c = t + it * 256;
            int r = c >> 2, cc = (c & 3) << 3;
            int ga = m0 + r; ga = ga < M ? ga : M - 1;
            *(uint4*)&Al[r][cc] = *(const uint4*)(A + (size_t)ga * K + k0 + cc);
            int gb = n0 + r; gb = gb < N ? gb : N - 1;
            *(uint4*)&Bl[r][cc] = *(const uint4*)(B + (size_t)gb * K + k0 + cc);
        }
        __syncthreads();
        bf16x8 af[4], bfr[4];
#pragma unroll
        for (int m = 0; m < 4; ++m) af[m] = *(const bf16x8*)&Al[wr * 64 + m * 16 + fr][fg * 8];
#pragma unroll
        for (int n = 0; n < 4; ++n) bfr[n] = *(const bf16x8*)&Bl[wc * 64 + n * 16 + fr][fg * 8];
#pragma unroll
        for (int m = 0; m < 4; ++m)
#pragma unroll
            for (int n = 0; n < 4; ++n)
                acc[m][n] = __builtin_amdgcn_mfma_f32_16x16x32_bf16(af[m], bfr[n], acc[m][n], 0, 0, 0);
        __syncthreads();
    }
#pragma unroll
    for (int m = 0; m < 4; ++m) {
#pragma unroll
        for (int n = 0; n < 4; ++n) {
            int col = n0 + wc * 64 + n * 16 + fr;
            float bv = bias[col];
#pragma unroll
            for (int r = 0; r < 4; ++r) {
                int row = m0 + wr * 64 + m * 16 + fg * 4 + r;
                if (row < M) {
                    float v = acc[m][n][r] + bv;
                    if (RES) v += res[(size_t)row * N + col];
                    if (ACT) v = v / (1.f + __expf(-1.702f * v));  // QuickGELU
                    if (OUTBF) ((u16*)Cp)[(size_t)row * N + col] = f2b(v);
                    else       ((float*)Cp)[(size_t)row * N + col] = v;
                }
            }
        }
    }
}

// ---------------- MFMA attention: one block per (b,h) ----------------
// S^T = K*Q^T (lane holds col q = lane&15), softmax per-lane + 2 shfl,
// O^T = V^T*P^T with P repacked via tiny per-wave LDS buffer.
__global__ __launch_bounds__(256, 2) void attn_kernel(
    const u16* __restrict__ qkv,   // [257*32][2304] rows m*32+b; q|k|v at +0/+768/+1536
    const u16* __restrict__ nq,    // [100*32][768]  rows q*32+b
    const u64* __restrict__ mpk,   // [32*100][5] packed mask bits (1 = blocked)
    u16* __restrict__ out)         // [357*32][768]  rows q*32+b
{
    __shared__ u16 Kl[272 * 64];   // K rows, XOR-swizzled: byte ^= (row&7)<<4
    __shared__ u16 Vt[64 * 296];   // Vt[d][m], row stride 592B (conflict-free frag reads)
    __shared__ u16 Pb[4][640];     // per-wave P chunk buffer [16][40]
    const int bid = blockIdx.x;
    const int b = bid / 12, h = bid % 12;
    const int t = threadIdx.x, lane = t & 63, wv = t >> 6;
    const int fr = lane & 15, fg = lane >> 4;

    // zero Vt pad columns 257..287 (so p=0 * garbage never makes NaN)
    for (int i = t; i < 2048; i += 256) {
        int d = i >> 5, c = 257 + (i & 31);
        if (c < 288) Vt[d * 296 + c] = 0;
    }
    // stage K (swizzled) and V^T
    {
        const int r8 = t >> 3, c8 = (t & 7) * 8;
        const u16* kb = qkv + 768 + h * 64 + c8;
        const u16* vb = qkv + 1536 + h * 64 + c8;
#pragma unroll 1
        for (int p = 0; p < 9; ++p) {
            int m = r8 + p * 32;
            if (m <= 256) {
                size_t go = (size_t)(m * 32 + b) * 2304;
                bf16x8 kv = *(const bf16x8*)(kb + go);
                int byte = m * 128 + c8 * 2;
                *(bf16x8*)((char*)Kl + (byte ^ ((m & 7) << 4))) = kv;
                bf16x8 vv = *(const bf16x8*)(vb + go);
#pragma unroll
                for (int j = 0; j < 8; ++j)
                    Vt[(c8 + j) * 296 + m] = (u16)vv[j];
            }
        }
    }
    __syncthreads();

    const int swzK = (fr & 7) << 4;
    char* pb = (char*)&Pb[wv][0];
    const char* KlB = (const char*)Kl;
    const char* VtB = (const char*)Vt;

    auto fetch = [&](int ti, bf16x8& q0v, bf16x8& q1v, u64* mw, bool& im) {
        int q = ti * 16 + fr;
        int qc = q < 357 ? q : 356;
        im = qc < 100;
        const u16* qp = im ? (nq + (size_t)(qc * 32 + b) * 768 + h * 64)
                           : (qkv + (size_t)((qc - 100) * 32 + b) * 2304 + h * 64);
        q0v = *(const bf16x8*)(qp + fg * 8);
        q1v = *(const bf16x8*)(qp + 32 + fg * 8);
        if (im) {
            const u64* mp = mpk + (size_t)(b * 100 + qc) * 5;
            mw[0] = mp[0]; mw[1] = mp[1]; mw[2] = mp[2]; mw[3] = mp[3]; mw[4] = mp[4];
        } else {
            mw[0] = mw[1] = mw[2] = mw[3] = mw[4] = 0;
        }
    };

    bf16x8 qf0, qf1, qn0, qn1;
    u64 mwc[5], mwn[5];
    bool imc, imn;
    fetch(wv, qf0, qf1, mwc, imc);

#pragma unroll 1
    for (int ti = wv; ti < 23; ti += 4) {
        // ---- QK^T (transposed: acc col = q) ----
        f32x4 sc[17];
#pragma unroll
        for (int kt = 0; kt < 17; ++kt) {
            int rb = (kt * 16 + fr) * 128;
            bf16x8 ka0 = *(const bf16x8*)(KlB + ((rb + fg * 16) ^ swzK));
            bf16x8 ka1 = *(const bf16x8*)(KlB + ((rb + 64 + fg * 16) ^ swzK));
            f32x4 a = {0.f, 0.f, 0.f, 0.f};
            a = __builtin_amdgcn_mfma_f32_16x16x32_bf16(ka0, qf0, a, 0, 0, 0);
            a = __builtin_amdgcn_mfma_f32_16x16x32_bf16(ka1, qf1, a, 0, 0, 0);
            sc[kt] = a;
        }
        // prefetch next tile's Q + mask (hide HBM latency under softmax/PV)
        if (ti + 4 < 23) fetch(ti + 4, qn0, qn1, mwn, imn);
        // ---- mask + row max ----
        float mx = -INFINITY;
#pragma unroll
        for (int kt = 0; kt < 17; ++kt) {
            u64 mw = (kt >> 2) == 0 ? mwc[0] : (kt >> 2) == 1 ? mwc[1] : (kt >> 2) == 2 ? mwc[2]
                   : (kt >> 2) == 3 ? mwc[3] : mwc[4];
#pragma unroll
            for (int r = 0; r < 4; ++r) {
                int key = kt * 16 + fg * 4 + r;
                bool bad = (key > 256) || (imc && ((mw >> (key & 63)) & 1ull));
                float s = bad ? -INFINITY : sc[kt][r];
                sc[kt][r] = s;
                mx = fmaxf(mx, s);
            }
        }
        mx = fmaxf(mx, __shfl_xor(mx, 16));
        mx = fmaxf(mx, __shfl_xor(mx, 32));
        // ---- exp (scale folded), sum, pack to bf16 pairs ----
        float l = 0.f;
        unsigned pk[17][2];
#pragma unroll
        for (int kt = 0; kt < 17; ++kt) {
            float p0 = __expf((sc[kt][0] - mx) * 0.125f);
            float p1 = __expf((sc[kt][1] - mx) * 0.125f);
            float p2 = __expf((sc[kt][2] - mx) * 0.125f);
            float p3 = __expf((sc[kt][3] - mx) * 0.125f);
            l += (p0 + p1) + (p2 + p3);
            pk[kt][0] = pack2(p0, p1);
            pk[kt][1] = pack2(p2, p3);
        }
        l += __shfl_xor(l, 16);
        l += __shfl_xor(l, 32);
        // ---- PV: O^T = V^T * P^T ----
        f32x4 oc[4] = {};
#pragma unroll
        for (int c = 0; c < 9; ++c) {
            uint2 w0; w0.x = pk[2 * c][0]; w0.y = pk[2 * c][1];
            *(uint2*)(pb + fr * 80 + fg * 8) = w0;
            uint2 w1;
            if (c < 8) { w1.x = pk[2 * c + 1][0]; w1.y = pk[2 * c + 1][1]; }
            else       { w1.x = 0; w1.y = 0; }
            *(uint2*)(pb + fr * 80 + 32 + fg * 8) = w1;
            bf16x8 pf = *(const bf16x8*)(pb + fr * 80 + fg * 16);
#pragma unroll
            for (int dt = 0; dt < 4; ++dt) {
                bf16x8 vf = *(const bf16x8*)(VtB + (dt * 16 + fr) * 592 + c * 64 + fg * 16);
                oc[dt] = __builtin_amdgcn_mfma_f32_16x16x32_bf16(vf, pf, oc[dt], 0, 0, 0);
            }
        }
        // ---- write O (lane q = fr, d = dt*16 + fg*4 + r) ----
        int q = ti * 16 + fr;
        if (q < 357) {
            float rl = 1.f / l;
            u16* op = out + (size_t)(q * 32 + b) * 768 + h * 64 + fg * 4;
#pragma unroll
            for (int dt = 0; dt < 4; ++dt) {
                ushort4 ov;
                ov.x = f2b(oc[dt][0] * rl); ov.y = f2b(oc[dt][1] * rl);
                ov.z = f2b(oc[dt][2] * rl); ov.w = f2b(oc[dt][3] * rl);
                *(ushort4*)(op + dt * 16) = ov;
            }
        }
        if (ti + 4 < 23) {
            qf0 = qn0; qf1 = qn1; imc = imn;
            mwc[0] = mwn[0]; mwc[1] = mwn[1]; mwc[2] = mwn[2]; mwc[3] = mwn[3]; mwc[4] = mwn[4];
        }
    }
}

// ---------------- launch ----------------
extern "C" void kernel_launch(void* const* d_in, const int* in_sizes, int n_in,
                              void* d_out, int out_size, void* d_ws, size_t ws_size,
                              hipStream_t stream)
{
    const float* y   = (const float*)d_in[0];
    const int*   msk = (const int*)  d_in[1];
    const float* ipw = (const float*)d_in[2];
    const float* ipb = (const float*)d_in[3];
    const float* nqw = (const float*)d_in[4];
    const float* nqb = (const float*)d_in[5];
    const float* ow  = (const float*)d_in[6];
    const float* ob  = (const float*)d_in[7];
    const float* l1g = (const float*)d_in[8];
    const float* l1b = (const float*)d_in[9];
    const float* l2g = (const float*)d_in[10];
    const float* l2b = (const float*)d_in[11];
    const float* fcw = (const float*)d_in[12];
    const float* fcb = (const float*)d_in[13];
    const float* pjw = (const float*)d_in[14];
    const float* pjb = (const float*)d_in[15];

    char* ws = (char*)d_ws;
    u16* x_b   = (u16*)(ws + 0);          // 11424 x 768
    u16* qkv_b = (u16*)(ws + 17547264);   //  8224 x 2304
    u16* nq_b  = (u16*)(ws + 55443456);   //  3200 x 768
    u16* ao_b  = (u16*)(ws + 60358656);   // 11424 x 768
    u16* h1_b  = (u16*)(ws + 0);          // 11424 x 3072 (phase 2, overlaps phase-1 region)
    u16* h_b   = (u16*)(ws + 77905920);   // 11424 x 768 (phase 2)
    u64* mpk_b = (u64*)(ws + 77905920);   // 3200 x 5 u64 (phase 1 only; dead before h_b written)
    u16* w_ip  = (u16*)(ws + 95453184);
    u16* w_nq  = (u16*)(ws + 98992128);
    u16* w_out = (u16*)(ws + 100171776);
    u16* w_fc  = (u16*)(ws + 101351424);
    u16* w_pj  = (u16*)(ws + 106070016);  // end 110,788,608 bytes
    float* out = (float*)d_out;

    cvt_kernel<<<1728, 256, 0, stream>>>(ipw, w_ip, 2304 * 768 / 4);
    cvt_kernel<<<576,  256, 0, stream>>>(nqw, w_nq, 768 * 768 / 4);
    cvt_kernel<<<576,  256, 0, stream>>>(ow,  w_out, 768 * 768 / 4);
    cvt_kernel<<<2304, 256, 0, stream>>>(fcw, w_fc, 3072 * 768 / 4);
    cvt_kernel<<<2304, 256, 0, stream>>>(pjw, w_pj, 3072 * 768 / 4);
    mask_pack<<<800, 256, 0, stream>>>(msk, mpk_b);

    // x = LN1(y) -> bf16
    ln_kernel<<<2856, 256, 0, stream>>>(y, l1g, l1b, x_b, 11424);
    // qkv = x[100:] @ in_proj_w.T + b
    gemm_bt<0, 1, 0><<<dim3(65, 18), 256, 0, stream>>>(x_b + (size_t)3200 * 768, w_ip, ipb, nullptr, qkv_b, 8224, 2304, 768);
    // new_q = x[:100] @ new_q_w.T + b
    gemm_bt<0, 1, 0><<<dim3(25, 6), 256, 0, stream>>>(x_b, w_nq, nqb, nullptr, nq_b, 3200, 768, 768);
    // attention
    attn_kernel<<<384, 256, 0, stream>>>(qkv_b, nq_b, mpk_b, ao_b);
    // y2 = y + attn_out @ out_w.T + out_b   -> d_out (f32)
    gemm_bt<0, 0, 1><<<dim3(90, 6), 256, 0, stream>>>(ao_b, w_out, ob, y, out, 11424, 768, 768);
    // h = LN2(y2) -> bf16
    ln_kernel<<<2856, 256, 0, stream>>>(out, l2g, l2b, h_b, 11424);
    // h1 = quickgelu(h @ fc_w.T + fc_b) -> bf16
    gemm_bt<1, 1, 0><<<dim3(90, 24), 256, 0, stream>>>(h_b, w_fc, fcb, nullptr, h1_b, 11424, 3072, 768);
    // out = y2 + h1 @ proj_w.T + proj_b
    gemm_bt<0, 0, 1><<<dim3(90, 6), 256, 0, stream>>>(h1_b, w_pj, pjb, out, out, 11424, 768, 3072);
}

// Round 3
// 505.504 us; speedup vs baseline: 2.8987x; 1.0408x over previous
//
#include <hip/hip_runtime.h>

// ResidualAttentionBlock on MI355X (gfx950).
// D=768 H=12 HD=64 NQ=100 KV=257 SEQ=357 BS=32.
// Round 3: gemm_bt staging via global_load_lds width-16 (m97 structure), fused weight cvt.

typedef short bf16x8 __attribute__((ext_vector_type(8)));
typedef float f32x4 __attribute__((ext_vector_type(4)));
typedef unsigned short u16;
typedef unsigned long long u64;

__device__ __forceinline__ u16 f2b(float f) {
    unsigned u = __builtin_bit_cast(unsigned, f);
    u = (u + 0x7fffu + ((u >> 16) & 1u)) >> 16;  // RNE
    return (u16)u;
}
__device__ __forceinline__ float b2f(u16 h) {
    unsigned u = ((unsigned)h) << 16;
    return __builtin_bit_cast(float, u);
}
__device__ __forceinline__ unsigned pack2(float a, float b) {
    return (unsigned)f2b(a) | ((unsigned)f2b(b) << 16);
}
// async global->LDS, 16B per lane; LDS dest = wave-uniform base + lane*16
__device__ __forceinline__ void g2l16(const void* g, void* l) {
    __builtin_amdgcn_global_load_lds(
        (__attribute__((address_space(1))) void*)g,
        (__attribute__((address_space(3))) void*)l, 16, 0, 0);
}

// ---------------- fused f32 -> bf16 conversion of all 5 weights ----------------
// dst regions are contiguous: ip(442368 f4) | nq(147456) | out(147456) | fc(589824) | pj(589824)
__global__ __launch_bounds__(256) void cvt5_kernel(
    const float* __restrict__ s0, const float* __restrict__ s1, const float* __restrict__ s2,
    const float* __restrict__ s3, const float* __restrict__ s4, u16* __restrict__ dst)
{
    int i = blockIdx.x * 256 + threadIdx.x;
    int stride = gridDim.x * 256;
    for (; i < 1916928; i += stride) {
        const float* src; int off;
        if (i < 442368)       { src = s0; off = i; }
        else if (i < 589824)  { src = s1; off = i - 442368; }
        else if (i < 737280)  { src = s2; off = i - 589824; }
        else if (i < 1327104) { src = s3; off = i - 737280; }
        else                  { src = s4; off = i - 1327104; }
        float4 v = ((const float4*)src)[off];
        ushort4 o;
        o.x = f2b(v.x); o.y = f2b(v.y); o.z = f2b(v.z); o.w = f2b(v.w);
        ((ushort4*)dst)[i] = o;
    }
}

// ---------------- mask -> packed bitmask [32*100][5] u64 ----------------
__global__ __launch_bounds__(256) void mask_pack(const int* __restrict__ m, u64* __restrict__ o) {
    int row = blockIdx.x * 4 + (threadIdx.x >> 6);
    int lane = threadIdx.x & 63;
    if (row >= 3200) return;
    const int* r = m + (size_t)row * 257;
    u64 w0 = __ballot(r[lane] != 0);
    u64 w1 = __ballot(r[64 + lane] != 0);
    u64 w2 = __ballot(r[128 + lane] != 0);
    u64 w3 = __ballot(r[192 + lane] != 0);
    u64 w4 = __ballot(lane == 0 && r[256] != 0);
    if (lane == 0) {
        u64* p = o + (size_t)row * 5;
        p[0] = w0; p[1] = w1; p[2] = w2; p[3] = w3; p[4] = w4;
    }
}

// ---------------- LayerNorm (fp32 in, bf16 out), one wave per row of 768 ----------------
__global__ __launch_bounds__(256) void ln_kernel(
    const float* __restrict__ in, const float* __restrict__ g, const float* __restrict__ be,
    u16* __restrict__ out, int nrows)
{
    int row = blockIdx.x * 4 + (threadIdx.x >> 6);
    int lane = threadIdx.x & 63;
    if (row >= nrows) return;
    const float* p = in + (size_t)row * 768;
    float4 a0 = *(const float4*)(p + lane * 4);
    float4 a1 = *(const float4*)(p + 256 + lane * 4);
    float4 a2 = *(const float4*)(p + 512 + lane * 4);
    float s = a0.x + a0.y + a0.z + a0.w + a1.x + a1.y + a1.z + a1.w + a2.x + a2.y + a2.z + a2.w;
    for (int o = 32; o; o >>= 1) s += __shfl_xor(s, o);
    float mean = s * (1.f / 768.f);
    float vs = 0.f;
#define SQA(t) { float dx; dx = t.x-mean; vs += dx*dx; dx = t.y-mean; vs += dx*dx; dx = t.z-mean; vs += dx*dx; dx = t.w-mean; vs += dx*dx; }
    SQA(a0) SQA(a1) SQA(a2)
#undef SQA
    for (int o = 32; o; o >>= 1) vs += __shfl_xor(vs, o);
    float rstd = rsqrtf(vs * (1.f / 768.f) + 1e-5f);
    u16* orow = out + (size_t)row * 768;
#pragma unroll
    for (int i = 0; i < 3; ++i) {
        int d = i * 256 + lane * 4;
        float4 av = (i == 0) ? a0 : ((i == 1) ? a1 : a2);
        float4 gv = *(const float4*)(g + d);
        float4 bv = *(const float4*)(be + d);
        ushort4 ov;
        ov.x = f2b((av.x - mean) * rstd * gv.x + bv.x);
        ov.y = f2b((av.y - mean) * rstd * gv.y + bv.y);
        ov.z = f2b((av.z - mean) * rstd * gv.z + bv.z);
        ov.w = f2b((av.w - mean) * rstd * gv.w + bv.w);
        *(ushort4*)(orow + d) = ov;
    }
}

// ---------------- bf16 MFMA GEMM: C[M][N] = A[M][K] @ B[N][K]^T + bias (+res) ----------------
// 128x128 tile, 4 waves (2x2), 4x4 16x16 frags/wave, BK=32, global_load_lds w16 staging (m97).
template<int ACT, int OUTBF, int RES>
__global__ __launch_bounds__(256) void gemm_bt(
    const u16* __restrict__ A, const u16* __restrict__ B,
    const float* __restrict__ bias, const float* __restrict__ res,
    void* __restrict__ Cp, int M, int N, int K)
{
    __shared__ u16 Al[128 * 32];
    __shared__ u16 Bl[128 * 32];
    const int t = threadIdx.x;
    const int lane = t & 63, w = t >> 6;
    const int wr = w >> 1, wc = w & 1;
    const int m0 = blockIdx.x * 128, n0 = blockIdx.y * 128;
    const int fr = lane & 15, fg = lane >> 4;

    // staging: wave w instr j covers LDS bytes [(w*2+j)*1024, +1024) = rows (w*2+j)*16..+16;
    // lane l -> row +(l>>2), 16B slot (l&3). Global source per-lane (row-clamped).
    const int srow = lane >> 2;
    const int scol = (lane & 3) * 8;  // element offset in 32-elem row
    int ar0 = m0 + w * 32 + srow;      int ar1 = ar0 + 16;
    ar0 = ar0 < M ? ar0 : M - 1;       ar1 = ar1 < M ? ar1 : M - 1;
    int br0 = n0 + w * 32 + srow;      int br1 = br0 + 16;
    br0 = br0 < N ? br0 : N - 1;       br1 = br1 < N ? br1 : N - 1;
    const u16* a0p = A + (size_t)ar0 * K + scol;
    const u16* a1p = A + (size_t)ar1 * K + scol;
    const u16* b0p = B + (size_t)br0 * K + scol;
    const u16* b1p = B + (size_t)br1 * K + scol;
    u16* al0 = &Al[(w * 2 + 0) * 512]; u16* al1 = &Al[(w * 2 + 1) * 512];
    u16* bl0 = &Bl[(w * 2 + 0) * 512]; u16* bl1 = &Bl[(w * 2 + 1) * 512];

    f32x4 acc[4][4] = {};
    for (int k0 = 0; k0 < K; k0 += 32) {
        g2l16(a0p + k0, al0);
        g2l16(a1p + k0, al1);
        g2l16(b0p + k0, bl0);
        g2l16(b1p + k0, bl1);
        __syncthreads();  // compiler drains vmcnt(0) before s_barrier
        bf16x8 af[4], bfr[4];
#pragma unroll
        for (int m = 0; m < 4; ++m) af[m] = *(const bf16x8*)&Al[(wr * 64 + m * 16 + fr) * 32 + fg * 8];
#pragma unroll
        for (int n = 0; n < 4; ++n) bfr[n] = *(const bf16x8*)&Bl[(wc * 64 + n * 16 + fr) * 32 + fg * 8];
#pragma unroll
        for (int m = 0; m < 4; ++m)
#pragma unroll
            for (int n = 0; n < 4; ++n)
                acc[m][n] = __builtin_amdgcn_mfma_f32_16x16x32_bf16(af[m], bfr[n], acc[m][n], 0, 0, 0);
        __syncthreads();
    }
    // Epilogue. C/D layout: col = lane&15, row = (lane>>4)*4 + r  [measured m89/m91]
#pragma unroll
    for (int m = 0; m < 4; ++m) {
#pragma unroll
        for (int n = 0; n < 4; ++n) {
            int col = n0 + wc * 64 + n * 16 + fr;
            float bv = bias[col];
#pragma unroll
            for (int r = 0; r < 4; ++r) {
                int row = m0 + wr * 64 + m * 16 + fg * 4 + r;
                if (row < M) {
                    float v = acc[m][n][r] + bv;
                    if (RES) v += res[(size_t)row * N + col];
                    if (ACT) v = v / (1.f + __expf(-1.702f * v));  // QuickGELU
                    if (OUTBF) ((u16*)Cp)[(size_t)row * N + col] = f2b(v);
                    else       ((float*)Cp)[(size_t)row * N + col] = v;
                }
            }
        }
    }
}

// ---------------- MFMA attention: one block per (b,h) ----------------
__global__ __launch_bounds__(256, 2) void attn_kernel(
    const u16* __restrict__ qkv,   // [257*32][2304] rows m*32+b; q|k|v at +0/+768/+1536
    const u16* __restrict__ nq,    // [100*32][768]  rows q*32+b
    const u64* __restrict__ mpk,   // [32*100][5] packed mask bits (1 = blocked)
    u16* __restrict__ out)         // [357*32][768]  rows q*32+b
{
    __shared__ u16 Kl[272 * 64];   // K rows, XOR-swizzled: byte ^= (row&7)<<4
    __shared__ u16 Vt[64 * 296];   // Vt[d][m], row stride 592B (conflict-free frag reads)
    __shared__ u16 Pb[4][640];     // per-wave P chunk buffer [16][40]
    const int bid = blockIdx.x;
    const int b = bid / 12, h = bid % 12;
    const int t = threadIdx.x, lane = t & 63, wv = t >> 6;
    const int fr = lane & 15, fg = lane >> 4;

    for (int i = t; i < 2048; i += 256) {
        int d = i >> 5, c = 257 + (i & 31);
        if (c < 288) Vt[d * 296 + c] = 0;
    }
    {
        const int r8 = t >> 3, c8 = (t & 7) * 8;
        const u16* kb = qkv + 768 + h * 64 + c8;
        const u16* vb = qkv + 1536 + h * 64 + c8;
#pragma unroll 1
        for (int p = 0; p < 9; ++p) {
            int m = r8 + p * 32;
            if (m <= 256) {
                size_t go = (size_t)(m * 32 + b) * 2304;
                bf16x8 kv = *(const bf16x8*)(kb + go);
                int byte = m * 128 + c8 * 2;
                *(bf16x8*)((char*)Kl + (byte ^ ((m & 7) << 4))) = kv;
                bf16x8 vv = *(const bf16x8*)(vb + go);
#pragma unroll
                for (int j = 0; j < 8; ++j)
                    Vt[(c8 + j) * 296 + m] = (u16)vv[j];
            }
        }
    }
    __syncthreads();

    const int swzK = (fr & 7) << 4;
    char* pb = (char*)&Pb[wv][0];
    const char* KlB = (const char*)Kl;
    const char* VtB = (const char*)Vt;

    auto fetch = [&](int ti, bf16x8& q0v, bf16x8& q1v, u64* mw, bool& im) {
        int q = ti * 16 + fr;
        int qc = q < 357 ? q : 356;
        im = qc < 100;
        const u16* qp = im ? (nq + (size_t)(qc * 32 + b) * 768 + h * 64)
                           : (qkv + (size_t)((qc - 100) * 32 + b) * 2304 + h * 64);
        q0v = *(const bf16x8*)(qp + fg * 8);
        q1v = *(const bf16x8*)(qp + 32 + fg * 8);
        if (im) {
            const u64* mp = mpk + (size_t)(b * 100 + qc) * 5;
            mw[0] = mp[0]; mw[1] = mp[1]; mw[2] = mp[2]; mw[3] = mp[3]; mw[4] = mp[4];
        } else {
            mw[0] = mw[1] = mw[2] = mw[3] = mw[4] = 0;
        }
    };

    bf16x8 qf0, qf1, qn0, qn1;
    u64 mwc[5], mwn[5];
    bool imc, imn;
    fetch(wv, qf0, qf1, mwc, imc);

#pragma unroll 1
    for (int ti = wv; ti < 23; ti += 4) {
        f32x4 sc[17];
#pragma unroll
        for (int kt = 0; kt < 17; ++kt) {
            int rb = (kt * 16 + fr) * 128;
            bf16x8 ka0 = *(const bf16x8*)(KlB + ((rb + fg * 16) ^ swzK));
            bf16x8 ka1 = *(const bf16x8*)(KlB + ((rb + 64 + fg * 16) ^ swzK));
            f32x4 a = {0.f, 0.f, 0.f, 0.f};
            a = __builtin_amdgcn_mfma_f32_16x16x32_bf16(ka0, qf0, a, 0, 0, 0);
            a = __builtin_amdgcn_mfma_f32_16x16x32_bf16(ka1, qf1, a, 0, 0, 0);
            sc[kt] = a;
        }
        if (ti + 4 < 23) fetch(ti + 4, qn0, qn1, mwn, imn);
        float mx = -INFINITY;
#pragma unroll
        for (int kt = 0; kt < 17; ++kt) {
            u64 mw = (kt >> 2) == 0 ? mwc[0] : (kt >> 2) == 1 ? mwc[1] : (kt >> 2) == 2 ? mwc[2]
                   : (kt >> 2) == 3 ? mwc[3] : mwc[4];
#pragma unroll
            for (int r = 0; r < 4; ++r) {
                int key = kt * 16 + fg * 4 + r;
                bool bad = (key > 256) || (imc && ((mw >> (key & 63)) & 1ull));
                float s = bad ? -INFINITY : sc[kt][r];
                sc[kt][r] = s;
                mx = fmaxf(mx, s);
            }
        }
        mx = fmaxf(mx, __shfl_xor(mx, 16));
        mx = fmaxf(mx, __shfl_xor(mx, 32));
        float l = 0.f;
        unsigned pk[17][2];
#pragma unroll
        for (int kt = 0; kt < 17; ++kt) {
            float p0 = __expf((sc[kt][0] - mx) * 0.125f);
            float p1 = __expf((sc[kt][1] - mx) * 0.125f);
            float p2 = __expf((sc[kt][2] - mx) * 0.125f);
            float p3 = __expf((sc[kt][3] - mx) * 0.125f);
            l += (p0 + p1) + (p2 + p3);
            pk[kt][0] = pack2(p0, p1);
            pk[kt][1] = pack2(p2, p3);
        }
        l += __shfl_xor(l, 16);
        l += __shfl_xor(l, 32);
        f32x4 oc[4] = {};
#pragma unroll
        for (int c = 0; c < 9; ++c) {
            uint2 w0; w0.x = pk[2 * c][0]; w0.y = pk[2 * c][1];
            *(uint2*)(pb + fr * 80 + fg * 8) = w0;
            uint2 w1;
            if (c < 8) { w1.x = pk[2 * c + 1][0]; w1.y = pk[2 * c + 1][1]; }
            else       { w1.x = 0; w1.y = 0; }
            *(uint2*)(pb + fr * 80 + 32 + fg * 8) = w1;
            bf16x8 pf = *(const bf16x8*)(pb + fr * 80 + fg * 16);
#pragma unroll
            for (int dt = 0; dt < 4; ++dt) {
                bf16x8 vf = *(const bf16x8*)(VtB + (dt * 16 + fr) * 592 + c * 64 + fg * 16);
                oc[dt] = __builtin_amdgcn_mfma_f32_16x16x32_bf16(vf, pf, oc[dt], 0, 0, 0);
            }
        }
        int q = ti * 16 + fr;
        if (q < 357) {
            float rl = 1.f / l;
            u16* op = out + (size_t)(q * 32 + b) * 768 + h * 64 + fg * 4;
#pragma unroll
            for (int dt = 0; dt < 4; ++dt) {
                ushort4 ov;
                ov.x = f2b(oc[dt][0] * rl); ov.y = f2b(oc[dt][1] * rl);
                ov.z = f2b(oc[dt][2] * rl); ov.w = f2b(oc[dt][3] * rl);
                *(ushort4*)(op + dt * 16) = ov;
            }
        }
        if (ti + 4 < 23) {
            qf0 = qn0; qf1 = qn1; imc = imn;
            mwc[0] = mwn[0]; mwc[1] = mwn[1]; mwc[2] = mwn[2]; mwc[3] = mwn[3]; mwc[4] = mwn[4];
        }
    }
}

// ---------------- launch ----------------
extern "C" void kernel_launch(void* const* d_in, const int* in_sizes, int n_in,
                              void* d_out, int out_size, void* d_ws, size_t ws_size,
                              hipStream_t stream)
{
    const float* y   = (const float*)d_in[0];
    const int*   msk = (const int*)  d_in[1];
    const float* ipw = (const float*)d_in[2];
    const float* ipb = (const float*)d_in[3];
    const float* nqw = (const float*)d_in[4];
    const float* nqb = (const float*)d_in[5];
    const float* ow  = (const float*)d_in[6];
    const float* ob  = (const float*)d_in[7];
    const float* l1g = (const float*)d_in[8];
    const float* l1b = (const float*)d_in[9];
    const float* l2g = (const float*)d_in[10];
    const float* l2b = (const float*)d_in[11];
    const float* fcw = (const float*)d_in[12];
    const float* fcb = (const float*)d_in[13];
    const float* pjw = (const float*)d_in[14];
    const float* pjb = (const float*)d_in[15];

    char* ws = (char*)d_ws;
    u16* x_b   = (u16*)(ws + 0);          // 11424 x 768
    u16* qkv_b = (u16*)(ws + 17547264);   //  8224 x 2304
    u16* nq_b  = (u16*)(ws + 55443456);   //  3200 x 768
    u16* ao_b  = (u16*)(ws + 60358656);   // 11424 x 768
    u16* h1_b  = (u16*)(ws + 0);          // 11424 x 3072 (phase 2, overlaps phase-1 region)
    u16* h_b   = (u16*)(ws + 77905920);   // 11424 x 768 (phase 2)
    u64* mpk_b = (u64*)(ws + 77905920);   // 3200 x 5 u64 (phase 1 only; dead before h_b written)
    u16* w_ip  = (u16*)(ws + 95453184);   // weights contiguous: ip|nq|out|fc|pj
    float* out = (float*)d_out;

    cvt5_kernel<<<2048, 256, 0, stream>>>(ipw, nqw, ow, fcw, pjw, w_ip);
    mask_pack<<<800, 256, 0, stream>>>(msk, mpk_b);

    u16* w_nq  = w_ip + 1769472;
    u16* w_out = w_nq + 589824;
    u16* w_fc  = w_out + 589824;
    u16* w_pj  = w_fc + 2359296;

    // x = LN1(y) -> bf16
    ln_kernel<<<2856, 256, 0, stream>>>(y, l1g, l1b, x_b, 11424);
    // qkv = x[100:] @ in_proj_w.T + b
    gemm_bt<0, 1, 0><<<dim3(65, 18), 256, 0, stream>>>(x_b + (size_t)3200 * 768, w_ip, ipb, nullptr, qkv_b, 8224, 2304, 768);
    // new_q = x[:100] @ new_q_w.T + b
    gemm_bt<0, 1, 0><<<dim3(25, 6), 256, 0, stream>>>(x_b, w_nq, nqb, nullptr, nq_b, 3200, 768, 768);
    // attention
    attn_kernel<<<384, 256, 0, stream>>>(qkv_b, nq_b, mpk_b, ao_b);
    // y2 = y + attn_out @ out_w.T + out_b   -> d_out (f32)
    gemm_bt<0, 0, 1><<<dim3(90, 6), 256, 0, stream>>>(ao_b, w_out, ob, y, out, 11424, 768, 768);
    // h = LN2(y2) -> bf16
    ln_kernel<<<2856, 256, 0, stream>>>(out, l2g, l2b, h_b, 11424);
    // h1 = quickgelu(h @ fc_w.T + fc_b) -> bf16
    gemm_bt<1, 1, 0><<<dim3(90, 24), 256, 0, stream>>>(h_b, w_fc, fcb, nullptr, h1_b, 11424, 3072, 768);
    // out = y2 + h1 @ proj_w.T + proj_b
    gemm_bt<0, 0, 1><<<dim3(90, 6), 256, 0, stream>>>(h1_b, w_pj, pjb, out, out, 11424, 768, 3072);
}

// Round 4
// 470.621 us; speedup vs baseline: 3.1135x; 1.0741x over previous
//
#include <hip/hip_runtime.h>

// ResidualAttentionBlock on MI355X (gfx950).
// D=768 H=12 HD=64 NQ=100 KV=257 SEQ=357 BS=32.
// Round 4: GEMM K-loop -> prefetch-ahead double-buffered LDS, single barrier per K-step
// (guide §5.5 T3 "minimum 2-phase" template, m248). Staging still global_load_lds w16.

typedef short bf16x8 __attribute__((ext_vector_type(8)));
typedef float f32x4 __attribute__((ext_vector_type(4)));
typedef unsigned short u16;
typedef unsigned long long u64;

__device__ __forceinline__ u16 f2b(float f) {
    unsigned u = __builtin_bit_cast(unsigned, f);
    u = (u + 0x7fffu + ((u >> 16) & 1u)) >> 16;  // RNE
    return (u16)u;
}
__device__ __forceinline__ float b2f(u16 h) {
    unsigned u = ((unsigned)h) << 16;
    return __builtin_bit_cast(float, u);
}
__device__ __forceinline__ unsigned pack2(float a, float b) {
    return (unsigned)f2b(a) | ((unsigned)f2b(b) << 16);
}
// async global->LDS, 16B per lane; LDS dest = wave-uniform base + lane*16
__device__ __forceinline__ void g2l16(const void* g, void* l) {
    __builtin_amdgcn_global_load_lds(
        (__attribute__((address_space(1))) void*)g,
        (__attribute__((address_space(3))) void*)l, 16, 0, 0);
}

// ---------------- fused f32 -> bf16 conversion of all 5 weights ----------------
__global__ __launch_bounds__(256) void cvt5_kernel(
    const float* __restrict__ s0, const float* __restrict__ s1, const float* __restrict__ s2,
    const float* __restrict__ s3, const float* __restrict__ s4, u16* __restrict__ dst)
{
    int i = blockIdx.x * 256 + threadIdx.x;
    int stride = gridDim.x * 256;
    for (; i < 1916928; i += stride) {
        const float* src; int off;
        if (i < 442368)       { src = s0; off = i; }
        else if (i < 589824)  { src = s1; off = i - 442368; }
        else if (i < 737280)  { src = s2; off = i - 589824; }
        else if (i < 1327104) { src = s3; off = i - 737280; }
        else                  { src = s4; off = i - 1327104; }
        float4 v = ((const float4*)src)[off];
        ushort4 o;
        o.x = f2b(v.x); o.y = f2b(v.y); o.z = f2b(v.z); o.w = f2b(v.w);
        ((ushort4*)dst)[i] = o;
    }
}

// ---------------- mask -> packed bitmask [32*100][5] u64 ----------------
__global__ __launch_bounds__(256) void mask_pack(const int* __restrict__ m, u64* __restrict__ o) {
    int row = blockIdx.x * 4 + (threadIdx.x >> 6);
    int lane = threadIdx.x & 63;
    if (row >= 3200) return;
    const int* r = m + (size_t)row * 257;
    u64 w0 = __ballot(r[lane] != 0);
    u64 w1 = __ballot(r[64 + lane] != 0);
    u64 w2 = __ballot(r[128 + lane] != 0);
    u64 w3 = __ballot(r[192 + lane] != 0);
    u64 w4 = __ballot(lane == 0 && r[256] != 0);
    if (lane == 0) {
        u64* p = o + (size_t)row * 5;
        p[0] = w0; p[1] = w1; p[2] = w2; p[3] = w3; p[4] = w4;
    }
}

// ---------------- LayerNorm (fp32 in, bf16 out), one wave per row of 768 ----------------
__global__ __launch_bounds__(256) void ln_kernel(
    const float* __restrict__ in, const float* __restrict__ g, const float* __restrict__ be,
    u16* __restrict__ out, int nrows)
{
    int row = blockIdx.x * 4 + (threadIdx.x >> 6);
    int lane = threadIdx.x & 63;
    if (row >= nrows) return;
    const float* p = in + (size_t)row * 768;
    float4 a0 = *(const float4*)(p + lane * 4);
    float4 a1 = *(const float4*)(p + 256 + lane * 4);
    float4 a2 = *(const float4*)(p + 512 + lane * 4);
    float s = a0.x + a0.y + a0.z + a0.w + a1.x + a1.y + a1.z + a1.w + a2.x + a2.y + a2.z + a2.w;
    for (int o = 32; o; o >>= 1) s += __shfl_xor(s, o);
    float mean = s * (1.f / 768.f);
    float vs = 0.f;
#define SQA(t) { float dx; dx = t.x-mean; vs += dx*dx; dx = t.y-mean; vs += dx*dx; dx = t.z-mean; vs += dx*dx; dx = t.w-mean; vs += dx*dx; }
    SQA(a0) SQA(a1) SQA(a2)
#undef SQA
    for (int o = 32; o; o >>= 1) vs += __shfl_xor(vs, o);
    float rstd = rsqrtf(vs * (1.f / 768.f) + 1e-5f);
    u16* orow = out + (size_t)row * 768;
#pragma unroll
    for (int i = 0; i < 3; ++i) {
        int d = i * 256 + lane * 4;
        float4 av = (i == 0) ? a0 : ((i == 1) ? a1 : a2);
        float4 gv = *(const float4*)(g + d);
        float4 bv = *(const float4*)(be + d);
        ushort4 ov;
        ov.x = f2b((av.x - mean) * rstd * gv.x + bv.x);
        ov.y = f2b((av.y - mean) * rstd * gv.y + bv.y);
        ov.z = f2b((av.z - mean) * rstd * gv.z + bv.z);
        ov.w = f2b((av.w - mean) * rstd * gv.w + bv.w);
        *(ushort4*)(orow + d) = ov;
    }
}

// ---------------- bf16 MFMA GEMM: C[M][N] = A[M][K] @ B[N][K]^T + bias (+res) ----------------
// 128x128 tile, 4 waves (2x2), 4x4 16x16 frags/wave, BK=32.
// Double-buffered LDS, prefetch-ahead staging, ONE barrier per K-step.
template<int ACT, int OUTBF, int RES>
__global__ __launch_bounds__(256) void gemm_bt(
    const u16* __restrict__ A, const u16* __restrict__ B,
    const float* __restrict__ bias, const float* __restrict__ res,
    void* __restrict__ Cp, int M, int N, int K)
{
    __shared__ u16 Al[2][128 * 32];
    __shared__ u16 Bl[2][128 * 32];
    const int t = threadIdx.x;
    const int lane = t & 63, w = t >> 6;
    const int wr = w >> 1, wc = w & 1;
    const int m0 = blockIdx.x * 128, n0 = blockIdx.y * 128;
    const int fr = lane & 15, fg = lane >> 4;

    // staging: wave w covers rows w*32..w*32+31 (2 instrs of 16 rows); lane l -> row +(l>>2),
    // 16B slot (l&3). LDS dest is wave-uniform base + lane*16; global src per-lane (row-clamped).
    const int srow = lane >> 2;
    const int scol = (lane & 3) * 8;
    int ar0 = m0 + w * 32 + srow;      int ar1 = ar0 + 16;
    ar0 = ar0 < M ? ar0 : M - 1;       ar1 = ar1 < M ? ar1 : M - 1;
    int br0 = n0 + w * 32 + srow;      int br1 = br0 + 16;
    br0 = br0 < N ? br0 : N - 1;       br1 = br1 < N ? br1 : N - 1;
    const u16* a0p = A + (size_t)ar0 * K + scol;
    const u16* a1p = A + (size_t)ar1 * K + scol;
    const u16* b0p = B + (size_t)br0 * K + scol;
    const u16* b1p = B + (size_t)br1 * K + scol;
    const int lo0 = (w * 2 + 0) * 512, lo1 = (w * 2 + 1) * 512;

    const int nk = K >> 5;
    // prologue: stage tile 0 into buf 0
    g2l16(a0p, &Al[0][lo0]);
    g2l16(a1p, &Al[0][lo1]);
    g2l16(b0p, &Bl[0][lo0]);
    g2l16(b1p, &Bl[0][lo1]);
    __syncthreads();

    f32x4 acc[4][4] = {};
#pragma unroll 2
    for (int ki = 0; ki < nk; ++ki) {
        const int cur = ki & 1;
        if (ki + 1 < nk) {               // issue next-tile loads BEFORE compute
            const int k0 = (ki + 1) << 5;
            const int nxt = cur ^ 1;
            g2l16(a0p + k0, &Al[nxt][lo0]);
            g2l16(a1p + k0, &Al[nxt][lo1]);
            g2l16(b0p + k0, &Bl[nxt][lo0]);
            g2l16(b1p + k0, &Bl[nxt][lo1]);
        }
        bf16x8 af[4], bfr[4];
#pragma unroll
        for (int m = 0; m < 4; ++m) af[m] = *(const bf16x8*)&Al[cur][(wr * 64 + m * 16 + fr) * 32 + fg * 8];
#pragma unroll
        for (int n = 0; n < 4; ++n) bfr[n] = *(const bf16x8*)&Bl[cur][(wc * 64 + n * 16 + fr) * 32 + fg * 8];
#pragma unroll
        for (int m = 0; m < 4; ++m)
#pragma unroll
            for (int n = 0; n < 4; ++n)
                acc[m][n] = __builtin_amdgcn_mfma_f32_16x16x32_bf16(af[m], bfr[n], acc[m][n], 0, 0, 0);
        __syncthreads();  // drains this wave's vmcnt(0) (next-tile loads) + barrier
    }
    // Epilogue. C/D layout: col = lane&15, row = (lane>>4)*4 + r  [measured m89/m91]
#pragma unroll
    for (int m = 0; m < 4; ++m) {
#pragma unroll
        for (int n = 0; n < 4; ++n) {
            int col = n0 + wc * 64 + n * 16 + fr;
            float bv = bias[col];
#pragma unroll
            for (int r = 0; r < 4; ++r) {
                int row = m0 + wr * 64 + m * 16 + fg * 4 + r;
                if (row < M) {
                    float v = acc[m][n][r] + bv;
                    if (RES) v += res[(size_t)row * N + col];
                    if (ACT) v = v / (1.f + __expf(-1.702f * v));  // QuickGELU
                    if (OUTBF) ((u16*)Cp)[(size_t)row * N + col] = f2b(v);
                    else       ((float*)Cp)[(size_t)row * N + col] = v;
                }
            }
        }
    }
}

// ---------------- MFMA attention: one block per (b,h) ----------------
__global__ __launch_bounds__(256, 2) void attn_kernel(
    const u16* __restrict__ qkv,   // [257*32][2304] rows m*32+b; q|k|v at +0/+768/+1536
    const u16* __restrict__ nq,    // [100*32][768]  rows q*32+b
    const u64* __restrict__ mpk,   // [32*100][5] packed mask bits (1 = blocked)
    u16* __restrict__ out)         // [357*32][768]  rows q*32+b
{
    __shared__ u16 Kl[272 * 64];   // K rows, XOR-swizzled: byte ^= (row&7)<<4
    __shared__ u16 Vt[64 * 296];   // Vt[d][m], row stride 592B (conflict-free frag reads)
    __shared__ u16 Pb[4][640];     // per-wave P chunk buffer [16][40]
    const int bid = blockIdx.x;
    const int b = bid / 12, h = bid % 12;
    const int t = threadIdx.x, lane = t & 63, wv = t >> 6;
    const int fr = lane & 15, fg = lane >> 4;

    for (int i = t; i < 2048; i += 256) {
        int d = i >> 5, c = 257 + (i & 31);
        if (c < 288) Vt[d * 296 + c] = 0;
    }
    {
        const int r8 = t >> 3, c8 = (t & 7) * 8;
        const u16* kb = qkv + 768 + h * 64 + c8;
        const u16* vb = qkv + 1536 + h * 64 + c8;
#pragma unroll 1
        for (int p = 0; p < 9; ++p) {
            int m = r8 + p * 32;
            if (m <= 256) {
                size_t go = (size_t)(m * 32 + b) * 2304;
                bf16x8 kv = *(const bf16x8*)(kb + go);
                int byte = m * 128 + c8 * 2;
                *(bf16x8*)((char*)Kl + (byte ^ ((m & 7) << 4))) = kv;
                bf16x8 vv = *(const bf16x8*)(vb + go);
#pragma unroll
                for (int j = 0; j < 8; ++j)
                    Vt[(c8 + j) * 296 + m] = (u16)vv[j];
            }
        }
    }
    __syncthreads();

    const int swzK = (fr & 7) << 4;
    char* pb = (char*)&Pb[wv][0];
    const char* KlB = (const char*)Kl;
    const char* VtB = (const char*)Vt;

    auto fetch = [&](int ti, bf16x8& q0v, bf16x8& q1v, u64* mw, bool& im) {
        int q = ti * 16 + fr;
        int qc = q < 357 ? q : 356;
        im = qc < 100;
        const u16* qp = im ? (nq + (size_t)(qc * 32 + b) * 768 + h * 64)
                           : (qkv + (size_t)((qc - 100) * 32 + b) * 2304 + h * 64);
        q0v = *(const bf16x8*)(qp + fg * 8);
        q1v = *(const bf16x8*)(qp + 32 + fg * 8);
        if (im) {
            const u64* mp = mpk + (size_t)(b * 100 + qc) * 5;
            mw[0] = mp[0]; mw[1] = mp[1]; mw[2] = mp[2]; mw[3] = mp[3]; mw[4] = mp[4];
        } else {
            mw[0] = mw[1] = mw[2] = mw[3] = mw[4] = 0;
        }
    };

    bf16x8 qf0, qf1, qn0, qn1;
    u64 mwc[5], mwn[5];
    bool imc, imn;
    fetch(wv, qf0, qf1, mwc, imc);

#pragma unroll 1
    for (int ti = wv; ti < 23; ti += 4) {
        f32x4 sc[17];
#pragma unroll
        for (int kt = 0; kt < 17; ++kt) {
            int rb = (kt * 16 + fr) * 128;
            bf16x8 ka0 = *(const bf16x8*)(KlB + ((rb + fg * 16) ^ swzK));
            bf16x8 ka1 = *(const bf16x8*)(KlB + ((rb + 64 + fg * 16) ^ swzK));
            f32x4 a = {0.f, 0.f, 0.f, 0.f};
            a = __builtin_amdgcn_mfma_f32_16x16x32_bf16(ka0, qf0, a, 0, 0, 0);
            a = __builtin_amdgcn_mfma_f32_16x16x32_bf16(ka1, qf1, a, 0, 0, 0);
            sc[kt] = a;
        }
        if (ti + 4 < 23) fetch(ti + 4, qn0, qn1, mwn, imn);
        float mx = -INFINITY;
#pragma unroll
        for (int kt = 0; kt < 17; ++kt) {
            u64 mw = (kt >> 2) == 0 ? mwc[0] : (kt >> 2) == 1 ? mwc[1] : (kt >> 2) == 2 ? mwc[2]
                   : (kt >> 2) == 3 ? mwc[3] : mwc[4];
#pragma unroll
            for (int r = 0; r < 4; ++r) {
                int key = kt * 16 + fg * 4 + r;
                bool bad = (key > 256) || (imc && ((mw >> (key & 63)) & 1ull));
                float s = bad ? -INFINITY : sc[kt][r];
                sc[kt][r] = s;
                mx = fmaxf(mx, s);
            }
        }
        mx = fmaxf(mx, __shfl_xor(mx, 16));
        mx = fmaxf(mx, __shfl_xor(mx, 32));
        float l = 0.f;
        unsigned pk[17][2];
#pragma unroll
        for (int kt = 0; kt < 17; ++kt) {
            float p0 = __expf((sc[kt][0] - mx) * 0.125f);
            float p1 = __expf((sc[kt][1] - mx) * 0.125f);
            float p2 = __expf((sc[kt][2] - mx) * 0.125f);
            float p3 = __expf((sc[kt][3] - mx) * 0.125f);
            l += (p0 + p1) + (p2 + p3);
            pk[kt][0] = pack2(p0, p1);
            pk[kt][1] = pack2(p2, p3);
        }
        l += __shfl_xor(l, 16);
        l += __shfl_xor(l, 32);
        f32x4 oc[4] = {};
#pragma unroll
        for (int c = 0; c < 9; ++c) {
            uint2 w0; w0.x = pk[2 * c][0]; w0.y = pk[2 * c][1];
            *(uint2*)(pb + fr * 80 + fg * 8) = w0;
            uint2 w1;
            if (c < 8) { w1.x = pk[2 * c + 1][0]; w1.y = pk[2 * c + 1][1]; }
            else       { w1.x = 0; w1.y = 0; }
            *(uint2*)(pb + fr * 80 + 32 + fg * 8) = w1;
            bf16x8 pf = *(const bf16x8*)(pb + fr * 80 + fg * 16);
#pragma unroll
            for (int dt = 0; dt < 4; ++dt) {
                bf16x8 vf = *(const bf16x8*)(VtB + (dt * 16 + fr) * 592 + c * 64 + fg * 16);
                oc[dt] = __builtin_amdgcn_mfma_f32_16x16x32_bf16(vf, pf, oc[dt], 0, 0, 0);
            }
        }
        int q = ti * 16 + fr;
        if (q < 357) {
            float rl = 1.f / l;
            u16* op = out + (size_t)(q * 32 + b) * 768 + h * 64 + fg * 4;
#pragma unroll
            for (int dt = 0; dt < 4; ++dt) {
                ushort4 ov;
                ov.x = f2b(oc[dt][0] * rl); ov.y = f2b(oc[dt][1] * rl);
                ov.z = f2b(oc[dt][2] * rl); ov.w = f2b(oc[dt][3] * rl);
                *(ushort4*)(op + dt * 16) = ov;
            }
        }
        if (ti + 4 < 23) {
            qf0 = qn0; qf1 = qn1; imc = imn;
            mwc[0] = mwn[0]; mwc[1] = mwn[1]; mwc[2] = mwn[2]; mwc[3] = mwn[3]; mwc[4] = mwn[4];
        }
    }
}

// ---------------- launch ----------------
extern "C" void kernel_launch(void* const* d_in, const int* in_sizes, int n_in,
                              void* d_out, int out_size, void* d_ws, size_t ws_size,
                              hipStream_t stream)
{
    const float* y   = (const float*)d_in[0];
    const int*   msk = (const int*)  d_in[1];
    const float* ipw = (const float*)d_in[2];
    const float* ipb = (const float*)d_in[3];
    const float* nqw = (const float*)d_in[4];
    const float* nqb = (const float*)d_in[5];
    const float* ow  = (const float*)d_in[6];
    const float* ob  = (const float*)d_in[7];
    const float* l1g = (const float*)d_in[8];
    const float* l1b = (const float*)d_in[9];
    const float* l2g = (const float*)d_in[10];
    const float* l2b = (const float*)d_in[11];
    const float* fcw = (const float*)d_in[12];
    const float* fcb = (const float*)d_in[13];
    const float* pjw = (const float*)d_in[14];
    const float* pjb = (const float*)d_in[15];

    char* ws = (char*)d_ws;
    u16* x_b   = (u16*)(ws + 0);          // 11424 x 768
    u16* qkv_b = (u16*)(ws + 17547264);   //  8224 x 2304
    u16* nq_b  = (u16*)(ws + 55443456);   //  3200 x 768
    u16* ao_b  = (u16*)(ws + 60358656);   // 11424 x 768
    u16* h1_b  = (u16*)(ws + 0);          // 11424 x 3072 (phase 2, overlaps phase-1 region)
    u16* h_b   = (u16*)(ws + 77905920);   // 11424 x 768 (phase 2)
    u64* mpk_b = (u64*)(ws + 77905920);   // 3200 x 5 u64 (phase 1 only; dead before h_b written)
    u16* w_ip  = (u16*)(ws + 95453184);   // weights contiguous: ip|nq|out|fc|pj
    float* out = (float*)d_out;

    cvt5_kernel<<<2048, 256, 0, stream>>>(ipw, nqw, ow, fcw, pjw, w_ip);
    mask_pack<<<800, 256, 0, stream>>>(msk, mpk_b);

    u16* w_nq  = w_ip + 1769472;
    u16* w_out = w_nq + 589824;
    u16* w_fc  = w_out + 589824;
    u16* w_pj  = w_fc + 2359296;

    // x = LN1(y) -> bf16
    ln_kernel<<<2856, 256, 0, stream>>>(y, l1g, l1b, x_b, 11424);
    // qkv = x[100:] @ in_proj_w.T + b
    gemm_bt<0, 1, 0><<<dim3(65, 18), 256, 0, stream>>>(x_b + (size_t)3200 * 768, w_ip, ipb, nullptr, qkv_b, 8224, 2304, 768);
    // new_q = x[:100] @ new_q_w.T + b
    gemm_bt<0, 1, 0><<<dim3(25, 6), 256, 0, stream>>>(x_b, w_nq, nqb, nullptr, nq_b, 3200, 768, 768);
    // attention
    attn_kernel<<<384, 256, 0, stream>>>(qkv_b, nq_b, mpk_b, ao_b);
    // y2 = y + attn_out @ out_w.T + out_b   -> d_out (f32)
    gemm_bt<0, 0, 1><<<dim3(90, 6), 256, 0, stream>>>(ao_b, w_out, ob, y, out, 11424, 768, 768);
    // h = LN2(y2) -> bf16
    ln_kernel<<<2856, 256, 0, stream>>>(out, l2g, l2b, h_b, 11424);
    // h1 = quickgelu(h @ fc_w.T + fc_b) -> bf16
    gemm_bt<1, 1, 0><<<dim3(90, 24), 256, 0, stream>>>(h_b, w_fc, fcb, nullptr, h1_b, 11424, 3072, 768);
    // out = y2 + h1 @ proj_w.T + proj_b
    gemm_bt<0, 0, 1><<<dim3(90, 6), 256, 0, stream>>>(h1_b, w_pj, pjb, out, out, 11424, 768, 3072);
}